// Round 10
// baseline (17163.275 us; speedup 1.0000x reference)
//
#include <hip/hip_runtime.h>

// BiLSTM tagger, MI355X. Round 10: dual-path (L2 + MALL) exchange, fp16 weights in LDS.
//  r9 post-mortem: asm-pinned weight arrays land in SCRATCH (VGPR=40 proves it) — every
//  register-residency attempt fails; LDS is the only controllable weight store (r6's
//  mechanism, minus its bank conflicts). The binding term is the exchange: agent atomics
//  are MALL-serviced (~900cy RT). Fix: producer publishes tagged u64 on TWO paths —
//  volatile store (write-through -> producer-XCD L2, fast for same-XCD readers) and
//  agent store (MALL, always correct). Consumer polls L2 slot every iter, MALL every 4th.
//  Placement heuristic: 256 blocks, workers b%8==0 (fw) / b%8==4 (bw) -> each direction's
//  32 WGs co-locate on one XCD if dispatch round-robins %8; correctness placement-free.
//  k_recurrent: 32 WG/dir x 256 thr; WG owns 8 units (32 gate rows); thread=(row rl, kq
//  32-k). Weights: fp16 LDS, lane-linear b128 (conflict-free). h: fp16 LDS, stride-40
//  chunks (kq windows hit disjoint banks). Activations gather-free on 8 lanes. lgkm-only
//  barriers. Pregate ring distance 2. k_prep2 mirrors Whh->fp16 into dead embeds region.
//
// Workspace (d_ws), ~92.6 MB used:
//   [0)        preC 256 KB   [262144) whhTc 256 KB
//   [524288)   embeds 12 MB  (k_prep2 overlays whh16 fp16 mirror, 1 MB, after k_pregate)
//   [13107200) pregates 64 MB [dir][t][u>>3][q*8+(u&7)]
//   [80216064) hout 16 MB
//   [96993280) exM 4 KB  [2 dir][2 par][128 u64]   (MALL path)
//   [96997376) exL 4 KB  [2 dir][2 par][128 u64]   (L2 fast path)

#define S_LEN 8192
#define LC    16
#define DW    256
#define DC    64
#define HC    128
#define H2    256
#define NG    1024   // 4*H2
#define NTAG  64
#define CV    128

typedef _Float16 f16x2 __attribute__((ext_vector_type(2)));
union F4H { float4 f4; f16x2 h2[4]; };

__device__ __forceinline__ float dot2f(f16x2 a, f16x2 b, float c){
#if __has_builtin(__builtin_amdgcn_fdot2)
  return __builtin_amdgcn_fdot2(a, b, c, false);
#else
  return c + (float)a[0]*(float)b[0] + (float)a[1]*(float)b[1];
#endif
}
__device__ __forceinline__ float sigmoid_f(float x){
  return __frcp_rn(1.0f + __expf(-x));
}
__device__ __forceinline__ float tanh_f(float x){
  float a = fabsf(x);
  float t = 1.0f - 2.0f * __frcp_rn(__expf(2.0f*a) + 1.0f);
  return copysignf(t, x);
}

// ---------------------------------------------------------------- k_prep
__global__ __launch_bounds__(512) void k_prep(
    const float* __restrict__ char_emb, const float* __restrict__ char_Wih,
    const float* __restrict__ char_Whh, const float* __restrict__ char_b,
    float* __restrict__ preC, float* __restrict__ whhTc)
{
  int blk = blockIdx.x, tid = threadIdx.x;
  __shared__ float esh[DC];
  if (blk < CV){
    if (tid < DC) esh[tid] = char_emb[blk*DC + tid];
    __syncthreads();
    const float* wr = char_Wih + (size_t)tid*DC;
    float acc = char_b[tid];
#pragma unroll
    for (int d=0; d<DC; d+=4){
      float4 wv = *(const float4*)&wr[d];
      acc += wv.x*esh[d] + wv.y*esh[d+1] + wv.z*esh[d+2] + wv.w*esh[d+3];
    }
    preC[(size_t)blk*512 + tid] = acc;
  } else {
    int k = blk - CV;
    whhTc[(size_t)k*512 + tid] = char_Whh[(size_t)tid*HC + k];
  }
}

// ---------------------------------------------------------------- k_char_lstm
__global__ __launch_bounds__(256) void k_char_lstm(
    const int* __restrict__ charsets, const int* __restrict__ lengths,
    const float* __restrict__ preC, const float* __restrict__ whhTc,
    float* __restrict__ embeds)
{
  int blk = blockIdx.x, tid = threadIdx.x;
  int s0 = blk*16;
  __shared__ float h_sh[16][132];
  __shared__ float gsh[512][17];
  __shared__ int   ch_sh[16];

  for (int i = tid; i < 16*132; i += 256) (&h_sh[0][0])[i] = 0.0f;

  int uw  = tid & 15;
  int ujg = tid >> 4;
  float c[8];
#pragma unroll
  for (int u=0; u<8; u++) c[u] = 0.0f;
  int lw = lengths[s0 + uw];

  int g0 = tid, g1 = tid + 256;
  __syncthreads();

  for (int t=0; t<LC; t++){
    if (tid < 16) ch_sh[tid] = charsets[(size_t)(s0+tid)*LC + t];
    __syncthreads();                                        // (A)

    float acc0[16], acc1[16];
#pragma unroll
    for (int w=0; w<16; w++){
      int ch = ch_sh[w];
      acc0[w] = preC[(size_t)ch*512 + g0];
      acc1[w] = preC[(size_t)ch*512 + g1];
    }
    for (int k4=0; k4<HC; k4+=4){
      float w00 = whhTc[(size_t)(k4+0)*512 + g0];
      float w01 = whhTc[(size_t)(k4+1)*512 + g0];
      float w02 = whhTc[(size_t)(k4+2)*512 + g0];
      float w03 = whhTc[(size_t)(k4+3)*512 + g0];
      float w10 = whhTc[(size_t)(k4+0)*512 + g1];
      float w11 = whhTc[(size_t)(k4+1)*512 + g1];
      float w12 = whhTc[(size_t)(k4+2)*512 + g1];
      float w13 = whhTc[(size_t)(k4+3)*512 + g1];
#pragma unroll
      for (int w=0; w<16; w++){
        float4 h4 = *(const float4*)&h_sh[w][k4];
        acc0[w] += w00*h4.x + w01*h4.y + w02*h4.z + w03*h4.w;
        acc1[w] += w10*h4.x + w11*h4.y + w12*h4.z + w13*h4.w;
      }
    }
#pragma unroll
    for (int w=0; w<16; w++){ gsh[g0][w] = acc0[w]; gsh[g1][w] = acc1[w]; }
    __syncthreads();                                        // (G)

    float hnew[8];
#pragma unroll
    for (int u=0; u<8; u++){
      int j = ujg*8 + u;
      float gi = sigmoid_f(gsh[j][uw]);
      float gf = sigmoid_f(gsh[HC + j][uw]);
      float gg = tanh_f   (gsh[2*HC + j][uw]);
      float go = sigmoid_f(gsh[3*HC + j][uw]);
      c[u] = gf*c[u] + gi*gg;
      hnew[u] = go * tanh_f(c[u]);
    }
#pragma unroll
    for (int u=0; u<8; u+=4)
      *(float4*)&h_sh[uw][ujg*8 + u] = make_float4(hnew[u],hnew[u+1],hnew[u+2],hnew[u+3]);
    if (t == lw-1){
#pragma unroll
      for (int u=0; u<8; u+=4)
        *(float4*)&embeds[(size_t)(s0+uw)*384 + ujg*8 + u]
            = make_float4(hnew[u],hnew[u+1],hnew[u+2],hnew[u+3]);
    }
  }
}

// ---------------------------------------------------------------- k_gather
__global__ __launch_bounds__(256) void k_gather(
    const int* __restrict__ sentence, const float* __restrict__ word_emb,
    float* __restrict__ embeds)
{
  int blk = blockIdx.x, tid = threadIdx.x;
  int s = blk*8 + (tid >> 5);
  int lane = tid & 31;
  int idx = sentence[s];
  const float4* src = (const float4*)(word_emb + (size_t)idx*DW);
  float4* dst = (float4*)(embeds + (size_t)s*384 + 128);
  dst[lane]      = src[lane];
  dst[lane + 32] = src[lane + 32];
}

// ---------------------------------------------------------------- k_pregate
// Output layout: pregates[dir][t][u>>3][q*8 + (u&7)]
__global__ __launch_bounds__(256) void k_pregate(
    const float* __restrict__ embeds,
    const float* __restrict__ Wih_fw, const float* __restrict__ b_fw,
    const float* __restrict__ Wih_bw, const float* __restrict__ b_bw,
    float* __restrict__ pregates)
{
  int dir = blockIdx.z;
  const float* W    = dir ? Wih_bw : Wih_fw;
  const float* bias = dir ? b_bw   : b_fw;
  int t0 = blockIdx.x*64, n0 = blockIdx.y*64;
  __shared__ float a_sh[16][68];
  __shared__ float b_sh[16][68];
  int tid = threadIdx.x;
  int li = tid & 63, kq = tid >> 6;
  int ti = tid >> 4, tj = tid & 15;
  float acc[4][4];
#pragma unroll
  for (int ii=0; ii<4; ii++)
#pragma unroll
    for (int jj=0; jj<4; jj++) acc[ii][jj] = 0.0f;

  for (int k0=0; k0<384; k0+=16){
    float4 av = *(const float4*)&embeds[(size_t)(t0+li)*384 + k0 + kq*4];
    float4 bv = *(const float4*)&W     [(size_t)(n0+li)*384 + k0 + kq*4];
    __syncthreads();
    a_sh[kq*4+0][li]=av.x; a_sh[kq*4+1][li]=av.y; a_sh[kq*4+2][li]=av.z; a_sh[kq*4+3][li]=av.w;
    b_sh[kq*4+0][li]=bv.x; b_sh[kq*4+1][li]=bv.y; b_sh[kq*4+2][li]=bv.z; b_sh[kq*4+3][li]=bv.w;
    __syncthreads();
#pragma unroll
    for (int kk=0; kk<16; kk++){
      float4 a4 = *(const float4*)&a_sh[kk][ti*4];
      float4 b4 = *(const float4*)&b_sh[kk][tj*4];
      float aa[4] = {a4.x,a4.y,a4.z,a4.w};
      float bb[4] = {b4.x,b4.y,b4.z,b4.w};
#pragma unroll
      for (int ii=0; ii<4; ii++)
#pragma unroll
        for (int jj=0; jj<4; jj++) acc[ii][jj] += aa[ii]*bb[jj];
    }
  }
  float4 bias4 = *(const float4*)&bias[n0 + tj*4];
  float bb2[4] = {bias4.x,bias4.y,bias4.z,bias4.w};
  int q = n0 >> 8;
#pragma unroll
  for (int ii=0; ii<4; ii++){
    size_t base = ((size_t)dir*S_LEN + (t0+ti*4+ii))*NG;
#pragma unroll
    for (int jj=0; jj<4; jj++){
      int u = (n0 & 255) + tj*4 + jj;
      pregates[base + (size_t)(u>>3)*32 + q*8 + (u&7)] = acc[ii][jj] + bb2[jj];
    }
  }
}

// ---------------------------------------------------------------- k_prep2
// fp16 mirror of Whh, laid out exactly as k_recurrent's LDS staging expects:
// whh16[((dir*32+wgi)*16 + w*4+j)*512 + l*8 + e], thread map identical to k_recurrent.
__global__ __launch_bounds__(256) void k_prep2(
    const float* __restrict__ Whh_fw, const float* __restrict__ Whh_bw,
    _Float16* __restrict__ whh16)
{
  int b = blockIdx.x;              // 64 = dir*32 + wgi
  int dir = b >> 5, wgi = b & 31;
  int tid = threadIdx.x;
  int w = tid >> 6, l = tid & 63;
  int rl = tid >> 3, kq = tid & 7;
  int q = rl >> 3, ul = rl & 7;
  int R = q*H2 + wgi*8 + ul;
  const float* Whh = dir ? Whh_bw : Whh_fw;
  const float* wr = Whh + (size_t)R*H2 + kq*32;
  _Float16* dst = whh16 + (size_t)(dir*32+wgi)*16*512;
#pragma unroll
  for (int j=0; j<4; j++){
#pragma unroll
    for (int e=0; e<8; e++)
      dst[(size_t)(w*4+j)*512 + l*8 + e] = (_Float16)wr[j*8 + e];
  }
}

// ---------------------------------------------------------------- k_recurrent
__global__ __launch_bounds__(256, 1) void k_recurrent(
    const _Float16* __restrict__ whh16_all,
    const float* __restrict__ pgb_all,
    unsigned long long* __restrict__ exM,
    unsigned long long* __restrict__ exL,
    float* __restrict__ hout)
{
  int b = blockIdx.x;              // 256 blocks; workers b%8==0 (fw) / b%8==4 (bw)
  int m = b & 7;
  if (m != 0 && m != 4) return;
  int dir = (m == 4) ? 1 : 0;
  int wgi = b >> 3;                // 0..31
  int tid = threadIdx.x;
  int w = tid >> 6, l = tid & 63;
  int rl = tid >> 3, kq = tid & 7; // row-in-WG 0..31 (q=rl>>3,ul=rl&7), 32-k slice

  const _Float16* wsrc = whh16_all + (size_t)(dir*32+wgi)*16*512;
  const float* pgb = pgb_all + (size_t)dir * S_LEN * NG;
  unsigned long long* __restrict__ exMb = exM + (size_t)dir*2*128;
  unsigned long long* __restrict__ exLb = exL + (size_t)dir*2*128;

  __shared__ __align__(16) float4    wlds[16*64];    // 16 KB, lane-linear b128
  __shared__ __align__(16) _Float16 h16[2][8*40];    // ph(k)=(k>>5)*40+(k&31)
  __shared__ float gacc[32];

  // stage weights (coalesced global -> LDS, one time)
#pragma unroll
  for (int j=0; j<4; j++)
    wlds[(w*4+j)*64 + l] = *(const float4*)&wsrc[(size_t)(w*4+j)*512 + l*8];
  for (int k = tid; k < H2; k += 256) h16[0][(k>>5)*40 + (k&31)] = (_Float16)0.0f;
  __syncthreads();

  int pgidx = wgi*32 + rl;
  float pgv = 0.0f, pgn = 0.0f;
  if (kq == 0){
    int ta = dir ? (S_LEN-1) : 0, tb = dir ? (S_LEN-2) : 1;
    pgv = pgb[(size_t)ta*NG + pgidx];
    pgn = pgb[(size_t)tb*NG + pgidx];
  }
  float c = 0.0f;

  for (int s=0; s<S_LEN; s++){
    int par = s & 1;
    int t = dir ? (S_LEN-1-s) : s;
    float pg2 = 0.0f;
    if (kq == 0){
      int s2 = (s+2 < S_LEN) ? (s+2) : (S_LEN-1);
      int t2 = dir ? (S_LEN-1-s2) : s2;
      pg2 = pgb[(size_t)t2*NG + pgidx];          // distance-2 ring prefetch
    }

    // matvec: row rl x k-slice [kq*32, kq*32+32) in fp16
    const _Float16* hbuf = h16[par];
    float aa0 = 0.0f, aa1 = 0.0f;
#pragma unroll
    for (int j=0; j<4; j++){
      F4H wv; wv.f4 = wlds[(w*4+j)*64 + l];
      F4H hv; hv.f4 = *(const float4*)&hbuf[kq*40 + j*8];
      aa0 = dot2f(wv.h2[0], hv.h2[0], aa0);
      aa1 = dot2f(wv.h2[1], hv.h2[1], aa1);
      aa0 = dot2f(wv.h2[2], hv.h2[2], aa0);
      aa1 = dot2f(wv.h2[3], hv.h2[3], aa1);
    }
    float a = aa0 + aa1;
    a += __shfl_xor(a, 1);       // reduce over kq (lane bits 0..2)
    a += __shfl_xor(a, 2);
    a += __shfl_xor(a, 4);
    if (kq == 0) gacc[rl] = a + pgv;
    asm volatile("s_waitcnt lgkmcnt(0)\n\ts_barrier" ::: "memory");   // B1 (LDS only)

    if (w == 0 && l < 8){
      // gather-free activations: lane l = unit ul, reads its 4 gate rows
      float xi = gacc[l], xf = gacc[8+l], xg = gacc[16+l], xo = gacc[24+l];
      float gi = sigmoid_f(xi);
      float gf = sigmoid_f(xf);
      float sg = sigmoid_f(xg + xg);
      float gg = sg + sg - 1.0f;             // tanh
      float go = sigmoid_f(xo);
      c = gf*c + gi*gg;
      float hn = go * tanh_f(c);
      hout[(size_t)t*512 + dir*H2 + wgi*8 + l] = hn;
      int k0 = wgi*8 + l;                    // own h -> local LDS
      h16[par^1][(k0>>5)*40 + (k0&31)] = (_Float16)hn;
      float hp = __shfl(hn, l+1);            // partner (lanes 0..7 all active)
      if ((l & 1) == 0 && s+1 < S_LEN){
        f16x2 pr; pr[0] = (_Float16)hn; pr[1] = (_Float16)hp;
        unsigned lo = __builtin_bit_cast(unsigned, pr);
        unsigned long long v =
            ((unsigned long long)(unsigned)(s+1) << 32) | (unsigned long long)lo;
        int slot = par*128 + wgi*4 + (l>>1);
        *(volatile unsigned long long*)&exLb[slot] = v;     // L2 fast path
        __hip_atomic_store(&exMb[slot], v,
                           __ATOMIC_RELAXED, __HIP_MEMORY_SCOPE_AGENT);  // MALL path
      }
    } else if (w == 1 && s+1 < S_LEN){
      // consumer wave: 2 slots/lane; L2 poll every iter, MALL fallback every 4th
      unsigned tag = (unsigned)(s+1);
      int sl1 = l, sl2 = l + 64;
      bool need1 = ((sl1 >> 2) != wgi), need2 = ((sl2 >> 2) != wgi);
      unsigned long long v1 = 0, v2 = 0;
      volatile unsigned long long* pl = (volatile unsigned long long*)(exLb + par*128);
      unsigned long long* pm = exMb + par*128;
      int it = 0;
      while (need1 | need2){
        if (need1){ unsigned long long v = pl[sl1];
                    if ((unsigned)(v>>32) == tag){ v1 = v; need1 = false; } }
        if (need2){ unsigned long long v = pl[sl2];
                    if ((unsigned)(v>>32) == tag){ v2 = v; need2 = false; } }
        if ((need1 | need2) && ((it & 3) == 3)){
          if (need1){ unsigned long long v =
                __hip_atomic_load(&pm[sl1], __ATOMIC_RELAXED, __HIP_MEMORY_SCOPE_AGENT);
              if ((unsigned)(v>>32) == tag){ v1 = v; need1 = false; } }
          if (need2){ unsigned long long v =
                __hip_atomic_load(&pm[sl2], __ATOMIC_RELAXED, __HIP_MEMORY_SCOPE_AGENT);
              if ((unsigned)(v>>32) == tag){ v2 = v; need2 = false; } }
        }
        it++;
      }
      if ((sl1 >> 2) != wgi){
        int k0 = (sl1>>2)*8 + (sl1&3)*2;
        *(f16x2*)&h16[par^1][(k0>>5)*40 + (k0&31)] =
            __builtin_bit_cast(f16x2, (unsigned)v1);
      }
      if ((sl2 >> 2) != wgi){
        int k0 = (sl2>>2)*8 + (sl2&3)*2;
        *(f16x2*)&h16[par^1][(k0>>5)*40 + (k0&31)] =
            __builtin_bit_cast(f16x2, (unsigned)v2);
      }
    }
    pgv = pgn; pgn = pg2;
    asm volatile("s_waitcnt lgkmcnt(0)\n\ts_barrier" ::: "memory");   // B2 (LDS only)
  }
}

// ---------------------------------------------------------------- k_output
__global__ __launch_bounds__(256) void k_output(
    const float* __restrict__ hout, const float* __restrict__ outW,
    const float* __restrict__ outb, float* __restrict__ out)
{
  __shared__ float wT[128][66];
  __shared__ float hsh[32][132];
  __shared__ float lsh[32][66];
  __shared__ float msh[32][2];
  int t0 = blockIdx.x*32, tid = threadIdx.x;
  int n  = tid & 63, tg = tid >> 6;
  int sl = tid >> 3, kg = tid & 7;
  int wn = tid & 63, wk = tid >> 6;
  float acc[8];
#pragma unroll
  for (int u=0; u<8; u++) acc[u] = 0.0f;

  for (int kc=0; kc<4; kc++){
    int k0 = kc*128;
    float4 wreg[8];
#pragma unroll
    for (int e=0; e<8; e++) wreg[e] = *(const float4*)&outW[(size_t)wn*512 + k0 + wk*32 + e*4];
    float4 hreg[4];
#pragma unroll
    for (int e=0; e<4; e++) hreg[e] = *(const float4*)&hout[(size_t)(t0+sl)*512 + k0 + kg*16 + e*4];
    __syncthreads();
#pragma unroll
    for (int e=0; e<8; e++){
      int kk = wk*32 + e*4;
      wT[kk+0][wn]=wreg[e].x; wT[kk+1][wn]=wreg[e].y; wT[kk+2][wn]=wreg[e].z; wT[kk+3][wn]=wreg[e].w;
    }
#pragma unroll
    for (int e=0; e<4; e++) *(float4*)&hsh[sl][kg*16 + e*4] = hreg[e];
    __syncthreads();
#pragma unroll
    for (int kk4=0; kk4<128; kk4+=4){
      float w0 = wT[kk4+0][n], w1 = wT[kk4+1][n], w2 = wT[kk4+2][n], w3 = wT[kk4+3][n];
#pragma unroll
      for (int u=0; u<8; u++){
        float4 h4 = *(const float4*)&hsh[tg*8+u][kk4];
        acc[u] += w0*h4.x + w1*h4.y + w2*h4.z + w3*h4.w;
      }
    }
  }
  float bn = outb[n];
#pragma unroll
  for (int u=0; u<8; u++) lsh[tg*8+u][n] = acc[u] + bn;
  __syncthreads();
  if (tid < 32){
    float M = -3.4e38f;
    for (int j=0; j<NTAG; j++) M = fmaxf(M, lsh[tid][j]);
    float ssum = 0.0f;
    for (int j=0; j<NTAG; j++) ssum += expf(lsh[tid][j] - M);
    msh[tid][0] = M; msh[tid][1] = logf(ssum);
  }
  __syncthreads();
#pragma unroll
  for (int u=0; u<8; u++){
    int tt = tg*8+u;
    out[(size_t)(t0+tt)*NTAG + n] = lsh[tt][n] - msh[tt][0] - msh[tt][1];
  }
}

// ---------------------------------------------------------------- launch
extern "C" void kernel_launch(void* const* d_in, const int* in_sizes, int n_in,
                              void* d_out, int out_size, void* d_ws, size_t ws_size,
                              hipStream_t stream)
{
  (void)in_sizes; (void)n_in; (void)out_size; (void)ws_size;
  const int*   sentence = (const int*)d_in[0];
  const int*   charsets = (const int*)d_in[1];
  const int*   char_len = (const int*)d_in[2];
  const float* word_emb = (const float*)d_in[3];
  const float* char_emb = (const float*)d_in[4];
  const float* char_Wih = (const float*)d_in[5];
  const float* char_Whh = (const float*)d_in[6];
  const float* char_b   = (const float*)d_in[7];
  const float* fw_Wih   = (const float*)d_in[8];
  const float* fw_Whh   = (const float*)d_in[9];
  const float* fw_b     = (const float*)d_in[10];
  const float* bw_Wih   = (const float*)d_in[11];
  const float* bw_Whh   = (const float*)d_in[12];
  const float* bw_b     = (const float*)d_in[13];
  const float* out_W    = (const float*)d_in[14];
  const float* out_b    = (const float*)d_in[15];
  float* out = (float*)d_out;

  char* ws = (char*)d_ws;
  float* preC     = (float*)(ws);
  float* whhTc    = (float*)(ws + 262144);
  float* embeds   = (float*)(ws + 524288);
  _Float16* whh16 = (_Float16*)(ws + 524288);   // overlays embeds after k_pregate
  float* pregates = (float*)(ws + 13107200);
  float* houtb    = (float*)(ws + 80216064);
  unsigned long long* exM = (unsigned long long*)(ws + 96993280);
  unsigned long long* exL = (unsigned long long*)(ws + 96997376);

  k_prep     <<<256,  512, 0, stream>>>(char_emb, char_Wih, char_Whh, char_b, preC, whhTc);
  k_char_lstm<<<512,  256, 0, stream>>>(charsets, char_len, preC, whhTc, embeds);
  k_gather   <<<1024, 256, 0, stream>>>(sentence, word_emb, embeds);
  k_pregate  <<<dim3(128,16,2), 256, 0, stream>>>(embeds, fw_Wih, fw_b, bw_Wih, bw_b, pregates);
  k_prep2    <<<64,   256, 0, stream>>>(fw_Whh, bw_Whh, whh16);
  k_recurrent<<<256,  256, 0, stream>>>(whh16, pregates, exM, exL, houtb);
  k_output   <<<256,  256, 0, stream>>>(houtb, out_W, out_b, out);
}